// Round 5
// baseline (166.342 us; speedup 1.0000x reference)
//
#include <hip/hip_runtime.h>

typedef __attribute__((ext_vector_type(8))) short short8;
typedef __attribute__((ext_vector_type(4))) float f32x4;
typedef __attribute__((ext_vector_type(4))) unsigned int u32x4;

#define NTOK 4096
#define DIM  256
#define P_STRIDE 72        // P row stride elems (144 B); chunk kc at pos = kc ^ (2*((r>>3)&1))
#define TILE_ELEMS 32768   // ushort elems per 64KB tile image (Ks 16384 | Kt 16384)

__device__ __forceinline__ unsigned pack2bf(float a, float b) {
  unsigned ua = __builtin_bit_cast(unsigned, a) + 0x8000u;
  unsigned ub = __builtin_bit_cast(unsigned, b) + 0x8000u;
  return __builtin_amdgcn_perm(ub, ua, 0x07060302u); // low=bf16(a), high=bf16(b)
}

// ---- prologue v2: single X read, LDS-staged transpose (verified R3) ------
__global__ __launch_bounds__(256, 4)
void prep_kernel(const float* __restrict__ X, unsigned short* __restrict__ Img) {
  __shared__ __align__(16) unsigned short rowbf[8 * 256];  // 4 KB bf16 stage
  const int b    = blockIdx.x & 3;
  const int sub  = blockIdx.x >> 2;   // 0..511
  const int t    = sub >> 3;
  const int part = sub & 7;
  const int tid  = threadIdx.x;
  const float* src = X + ((size_t)b * NTOK + t * 64 + part * 8) * DIM;
  unsigned short* dst = Img + ((size_t)(b * 64 + t)) * TILE_ELEMS;
  {
    const int r = tid >> 5;   // row within the 8-row slab
    const int c = tid & 31;   // 16B chunk within the row
    const float* s = src + r * DIM + c * 8;
    f32x4 f0 = *(const f32x4*)s;
    f32x4 f1 = *(const f32x4*)(s + 4);
    union { unsigned u[4]; u32x4 v; } p;
    p.u[0] = pack2bf(f0[0], f0[1]);
    p.u[1] = pack2bf(f0[2], f0[3]);
    p.u[2] = pack2bf(f1[0], f1[1]);
    p.u[3] = pack2bf(f1[2], f1[3]);
    const int gr = part * 8 + r;
    *(u32x4*)(dst + gr * 256 + ((c ^ (gr & 7)) << 3)) = p.v;
    *(u32x4*)(&rowbf[r * 256 + c * 8]) = p.v;
  }
  __syncthreads();
  {
    const int d = tid;        // one column per thread
    union { unsigned short s[8]; u32x4 v; } p;
    #pragma unroll
    for (int i = 0; i < 8; ++i) p.s[i] = rowbf[i * 256 + d];
    *(u32x4*)(dst + 16384 + part * 2048 + d * 8) = p.v;
  }
}

// ---- flash-attention: R4 structure + Kt in registers ---------------------
// LDS diet: ktb (64 KB) deleted. PV's B-operands (Kt) load straight from the
// L2/L1-resident Img into a static even/odd register double-buffer; the
// __syncthreads vmcnt(0) drain at each iter top lands them one iteration
// after issue (same contract the Ks DMA uses). This deletes per CU-iter:
// 64 bv ds_read_b128 (768 cyc) + their 4-way bank conflicts (512 cyc, the
// 8.39e6 counter) + Kt DMA LDS writes (256 cyc). Ks staging unchanged but
// spread over all 8 waves. P-store stays sunk below PV (R4 win).
__device__ __forceinline__ void pv_reg(const unsigned short* __restrict__ pr,
                                       const short8 (&bv)[2][4],
                                       f32x4 (&o)[2][4],
                                       int qh, int quad, int ln) {
  #pragma unroll
  for (int ks = 0; ks < 2; ++ks) {
    const int pos = (ks * 4 + quad) ^ ((ln >> 3) << 1);
    short8 ap[2];
    #pragma unroll
    for (int s = 0; s < 2; ++s)
      ap[s] = *(const short8*)(&pr[(qh * 32 + s * 16 + ln) * P_STRIDE + (pos << 3)]);
    #pragma unroll
    for (int s = 0; s < 2; ++s)
      #pragma unroll
      for (int dt = 0; dt < 4; ++dt)
        o[s][dt] = __builtin_amdgcn_mfma_f32_16x16x32_bf16(ap[s], bv[ks][dt], o[s][dt], 0, 0, 0);
  }
}

__global__ __launch_bounds__(512, 1)
void fa_kernel(const unsigned short* __restrict__ Img, float* __restrict__ Out) {
  __shared__ __align__(16) unsigned short ksb[2][16384];        // 64 KB (Ks dbuf)
  __shared__ __align__(16) unsigned short pb[2][64 * P_STRIDE]; // 18 KB (P dbuf)
  __shared__ float lbuf[64][4];                                 // 1 KB

  const int tid  = threadIdx.x;
  const int b    = blockIdx.x & 3;
  const int qblk = blockIdx.x >> 2;
  const int wave = tid >> 6;
  const int lane = tid & 63;
  const int ln   = lane & 15;
  const int quad = lane >> 4;
  const int swz  = ln & 7;
  const int qh   = wave & 1;
  const int role = wave >> 1;

  const unsigned short* imgb  = Img + (size_t)b * 64 * TILE_ELEMS;
  const char*           imgbc = (const char*)imgb;

  short8 aQ[2][8];
  #pragma unroll
  for (int s = 0; s < 2; ++s) {
    const unsigned short* qrow =
        imgb + (size_t)qblk * TILE_ELEMS + (qh * 32 + s * 16 + ln) * 256;
    #pragma unroll
    for (int ds = 0; ds < 8; ++ds)
      aQ[s][ds] = *(const short8*)(qrow + (((ds * 4 + quad) ^ swz) << 3));
  }

  f32x4 o[2][4];
  #pragma unroll
  for (int s = 0; s < 2; ++s)
    #pragma unroll
    for (int dt = 0; dt < 4; ++dt) o[s][dt] = (f32x4)(0.0f);
  float lrow[2][4] = {{0.f,0.f,0.f,0.f},{0.f,0.f,0.f,0.f}};

  const float c2 = 0.0901684400f;  // log2(e)/sqrt(256)

  // P write constants: kc = role*2 + (ln>>3); pos = kc ^ (2*(quad>>1))
  const int pwPos = ((role * 2 + (ln >> 3)) ^ ((quad >> 1) << 1)) << 3;
  const int pwCol = ln & 7;  // even lanes write dword covering cols (pwCol, pwCol+1)

  // Ks DMA: all 8 waves, 4 x 1KB each = 32KB/tile
  const char* gK = imgbc + (size_t)wave * 4096 + (size_t)lane * 16;
  #pragma unroll
  for (int i = 0; i < 4; ++i)
    __builtin_amdgcn_global_load_lds(
        (const __attribute__((address_space(1))) unsigned*)(gK + i * 1024),
        (__attribute__((address_space(3))) unsigned*)(&ksb[0][wave * 2048 + i * 512]),
        16, 0, 0);

  // Kt register-load base: kb = ks*4+quad, token col (role*64+ln), elem dt*128
  const unsigned short* ktg = imgb + 16384 + (size_t)quad * 2048 + (role * 64 + ln) * 8;

  short8 bvE[2][4];  // Kt(t) for even t
  short8 bvO[2][4];  // Kt(t) for odd t

  auto iter = [&](int t, short8 (&bvLd)[2][4], short8 (&bvUs)[2][4],
                  bool doPV) __attribute__((always_inline)) {
    __syncthreads();  // drains DMA(t) + bv(t-1); P(t-1)/Ks(t) ready
    const int buf = t & 1;

    // issue Ks(t+1) DMA
    if (t < 63) {
      const char* g = gK + (size_t)(t + 1) * 65536;
      unsigned short* l = &ksb[buf ^ 1][wave * 2048];
      #pragma unroll
      for (int i = 0; i < 4; ++i)
        __builtin_amdgcn_global_load_lds(
            (const __attribute__((address_space(1))) unsigned*)(g + i * 1024),
            (__attribute__((address_space(3))) unsigned*)(l + i * 512),
            16, 0, 0);
    }

    // issue bv(t) = Kt(t) register loads (consumed by PV at iter t+1)
    {
      const unsigned short* kt = ktg + (size_t)t * TILE_ELEMS;
      #pragma unroll
      for (int ks = 0; ks < 2; ++ks)
        #pragma unroll
        for (int dt = 0; dt < 4; ++dt)
          bvLd[ks][dt] = *(const short8*)(kt + ks * 8192 + dt * 128);
    }

    // --- QK(t): keys role*16..+15, both strips ---
    f32x4 sf0 = (f32x4)(0.0f), sf1 = (f32x4)(0.0f);
    {
      const unsigned short* krow = &ksb[buf][(role * 16 + ln) * 256];
      #pragma unroll
      for (int ds = 0; ds < 8; ++ds) {
        short8 bk = *(const short8*)(krow + (((ds * 4 + quad) ^ swz) << 3));
        sf0 = __builtin_amdgcn_mfma_f32_16x16x32_bf16(aQ[0][ds], bk, sf0, 0, 0, 0);
        sf1 = __builtin_amdgcn_mfma_f32_16x16x32_bf16(aQ[1][ds], bk, sf1, 0, 0, 0);
      }
    }

    // --- softmax numerators: compute only (regs); stored after PV ---
    unsigned pd0[4], pd1[4];
    #pragma unroll
    for (int j = 0; j < 4; ++j) {
      float p0 = __builtin_amdgcn_exp2f(sf0[j] * c2);
      float p1 = __builtin_amdgcn_exp2f(sf1[j] * c2);
      lrow[0][j] += p0;
      lrow[1][j] += p1;
      unsigned q0 = __builtin_bit_cast(unsigned, p0);
      unsigned q1 = __builtin_bit_cast(unsigned, p1);
      // partner (lane^1) via DPP quad_perm [1,0,3,2] = 0xB1 (pure VALU)
      unsigned n0 = (unsigned)__builtin_amdgcn_mov_dpp((int)q0, 0xB1, 0xF, 0xF, true);
      unsigned n1 = (unsigned)__builtin_amdgcn_mov_dpp((int)q1, 0xB1, 0xF, 0xF, true);
      pd0[j] = pack2bf(__builtin_bit_cast(float, q0), __builtin_bit_cast(float, n0));
      pd1[j] = pack2bf(__builtin_bit_cast(float, q1), __builtin_bit_cast(float, n1));
    }

    // --- PV(t-1): d-quarter role*64..+63, both strips, all 64 keys ---
    if (doPV)
      pv_reg(pb[buf ^ 1], bvUs, o, qh, quad, ln);

    // --- P-STORE(t): after PV's reads -> no alias pin (R4 win) ---
    if ((ln & 1) == 0) {
      unsigned short* pw = pb[buf];
      #pragma unroll
      for (int j = 0; j < 4; ++j) {
        const int r0 = qh * 32 + quad * 4 + j;
        *(unsigned*)(&pw[r0 * P_STRIDE + pwPos + pwCol]) = pd0[j];
        *(unsigned*)(&pw[(r0 + 16) * P_STRIDE + pwPos + pwCol]) = pd1[j];
      }
    }
  };

  iter(0, bvE, bvO, false);
  #pragma unroll 1
  for (int tt = 1; tt < 63; tt += 2) {
    iter(tt, bvO, bvE, true);
    iter(tt + 1, bvE, bvO, true);
  }
  iter(63, bvO, bvE, true);

  __syncthreads();  // drains bv(63); P(63) resident in pb[1]
  pv_reg(pb[1], bvO, o, qh, quad, ln);  // final tile

  // --- merge l across the 4 roles, divide, store ---
  #pragma unroll
  for (int off = 1; off < 16; off <<= 1)
    #pragma unroll
    for (int s = 0; s < 2; ++s)
      #pragma unroll
      for (int j = 0; j < 4; ++j)
        lrow[s][j] += __shfl_xor(lrow[s][j], off, 64);
  if (ln == 0) {
    #pragma unroll
    for (int s = 0; s < 2; ++s)
      #pragma unroll
      for (int j = 0; j < 4; ++j)
        lbuf[qh * 32 + s * 16 + quad * 4 + j][role] = lrow[s][j];
  }
  __syncthreads();

  #pragma unroll
  for (int s = 0; s < 2; ++s) {
    float* outp = Out + (size_t)(b * NTOK + qblk * 64 + qh * 32 + s * 16) * DIM + role * 64;
    #pragma unroll
    for (int j = 0; j < 4; ++j) {
      const int row = s * 16 + quad * 4 + j;
      f32x4 lv = *(const f32x4*)lbuf[qh * 32 + row];
      const float rl = 1.0f / (lv[0] + lv[1] + lv[2] + lv[3]);
      #pragma unroll
      for (int dt = 0; dt < 4; ++dt)
        outp[(size_t)(quad * 4 + j) * DIM + dt * 16 + ln] = o[s][dt][j] * rl;
    }
  }
}

extern "C" void kernel_launch(void* const* d_in, const int* in_sizes, int n_in,
                              void* d_out, int out_size, void* d_ws, size_t ws_size,
                              hipStream_t stream) {
  const float* X = (const float*)d_in[0];       // x: fp32 [4,4096,256]
  float* Out = (float*)d_out;                   // fp32 [4,4096,256]
  unsigned short* Img = (unsigned short*)d_ws;  // 16 MB bf16 tile images
  (void)in_sizes; (void)n_in; (void)out_size; (void)ws_size;
  hipLaunchKernelGGL(prep_kernel, dim3(2048), dim3(256), 0, stream, X, Img);
  hipLaunchKernelGGL(fa_kernel, dim3(256), dim3(512), 0, stream, Img, Out);
}